// Round 5
// baseline (219.692 us; speedup 1.0000x reference)
//
#include <hip/hip_runtime.h>
#include <hip/hip_bf16.h>

#define B_ 4
#define S_ 4096
#define D_ 1024
#define H_ 128

typedef unsigned short u16;
typedef unsigned int u32;
typedef short s16x8 __attribute__((ext_vector_type(8)));   // 8 bf16 (4 VGPRs)
typedef float f32x4 __attribute__((ext_vector_type(4)));   // MFMA 16x16 acc

__device__ __forceinline__ u16 f2bf(float f) {
    u32 x = __float_as_uint(f);
    u32 r = x + 0x7fffu + ((x >> 16) & 1u);   // RNE
    return (u16)(r >> 16);
}

// async global->LDS, 16 B per lane (m97 pattern; zero staging VGPRs)
__device__ __forceinline__ void gl_lds16(const u16* g, u16* l) {
    __builtin_amdgcn_global_load_lds(
        (const __attribute__((address_space(1))) u32*)g,
        (__attribute__((address_space(3))) u32*)l, 16, 0, 0);
}

// ---------------------------------------------------------------------------
// Kernel 0: input dtype detection (fp32 vs bf16). Verified in round 3.
// ---------------------------------------------------------------------------
__global__ void detect_dtype_kernel(const u32* __restrict__ w, int* __restrict__ flag) {
    __shared__ int smax[256];
    const int tid = threadIdx.x;
    int m = 0;
    for (int i = tid; i < 1024; i += 256) {
        u32 x = w[i];
        m = max(m, max((int)((x >> 7) & 0xFF), (int)((x >> 23) & 0xFF)));
    }
    smax[tid] = m;
    __syncthreads();
    if (tid == 0) {
        int mm = 0;
        for (int i = 0; i < 256; ++i) mm = max(mm, smax[i]);
        *flag = (mm >= 200) ? 1 : 0;
    }
}

// ---------------------------------------------------------------------------
// Kernel 0b: W -> Wt, bf16, transposed + tiled so a B-fragment is 16 B
// contiguous: Wt[((mat*32+kt)*128 + n)*32 + k]. Tile (mat,kt) = 8 KB.
// ---------------------------------------------------------------------------
__global__ __launch_bounds__(256) void prep_w_kernel(
    const void* __restrict__ Wq, const void* __restrict__ Wk, const void* __restrict__ Wv,
    u16* __restrict__ Wt, const int* __restrict__ dflag)
{
    const int kt = blockIdx.x, mat = blockIdx.y;
    const void* W = (mat == 0) ? Wq : (mat == 1) ? Wk : Wv;
    const int isf = *dflag;
    const int t = threadIdx.x;
    const int kk = t >> 3;            // 0..31 (k within tile)
    const int n0 = (t & 7) * 16;      // 16 n per thread
    u16 vals[16];
    if (isf) {
        const float* wp = (const float*)W + (size_t)(kt * 32 + kk) * H_ + n0;
#pragma unroll
        for (int i = 0; i < 16; ++i) vals[i] = f2bf(wp[i]);
    } else {
        const u16* wp = (const u16*)W + (size_t)(kt * 32 + kk) * H_ + n0;
#pragma unroll
        for (int i = 0; i < 16; ++i) vals[i] = wp[i];
    }
    const size_t base = (size_t)(mat * 32 + kt) * 128;
#pragma unroll
    for (int i = 0; i < 16; ++i)
        Wt[(base + n0 + i) * 32 + kk] = vals[i];
}

// ---------------------------------------------------------------------------
// Kernel 1: fused QKV GEMM v4 (unchanged from measured-good round).
// ---------------------------------------------------------------------------
__global__ __launch_bounds__(256) void qkv_kernel(
    const void* __restrict__ Xv, const u16* __restrict__ Wt,
    u16* __restrict__ Qo, u16* __restrict__ Ko, u16* __restrict__ Vto,
    const int* __restrict__ dflag)
{
    __shared__ u16 Ws[2][384 * 32];                              // 2 x 24 KB
    __shared__ union { u16 qk[32 * 136]; u16 vt[128 * 40]; } OsU; // 10.2 KB

    const int isf = *dflag;
    const int tid = threadIdx.x;
    const int w = tid >> 6, lane = tid & 63;
    const int r = lane & 15, q = lane >> 4;
    const size_t m0 = (size_t)blockIdx.x * 32;

    f32x4 acc[2][6];   // [row strip][frag]
#pragma unroll
    for (int s2 = 0; s2 < 2; ++s2)
#pragma unroll
        for (int i = 0; i < 6; ++i) acc[s2][i] = (f32x4){0.f, 0.f, 0.f, 0.f};

    const float* xf0 = (const float*)Xv + (m0 + r) * D_;
    const float* xf1 = (const float*)Xv + (m0 + 16 + r) * D_;
    const u16*   xb0 = (const u16*)Xv + (m0 + r) * D_;
    const u16*   xb1 = (const u16*)Xv + (m0 + 16 + r) * D_;

    float4 af[2][2];   // fp32 A prefetch (2 strips x 8 floats)
    uint4  ab[2];      // bf16 A prefetch

    // ---- async-stage W tile kt=0 into Ws[0] ----
#pragma unroll
    for (int i = 0; i < 6; ++i) {
        int c = tid + i * 256;      // 1536 chunks of 16 B; mat = c>>9
        gl_lds16(Wt + (size_t)((c >> 9) * 32) * 4096 + (c & 511) * 8, &Ws[0][c * 8]);
    }
    // ---- A prefetch kt=0 ----
    if (isf) {
        af[0][0] = *(const float4*)(xf0 + q * 8);
        af[0][1] = *(const float4*)(xf0 + q * 8 + 4);
        af[1][0] = *(const float4*)(xf1 + q * 8);
        af[1][1] = *(const float4*)(xf1 + q * 8 + 4);
    } else {
        ab[0] = *(const uint4*)(xb0 + q * 8);
        ab[1] = *(const uint4*)(xb1 + q * 8);
    }

    for (int kt = 0; kt < 32; ++kt) {
        const int buf = kt & 1;
        __syncthreads();   // drains vmcnt: Ws[buf] + A(kt) ready; readers of Ws[buf^1] done

        if (kt + 1 < 32) {  // async-stage W tile kt+1 into the other buffer
#pragma unroll
            for (int i = 0; i < 6; ++i) {
                int c = tid + i * 256;
                gl_lds16(Wt + (size_t)((c >> 9) * 32 + kt + 1) * 4096 + (c & 511) * 8,
                         &Ws[buf ^ 1][c * 8]);
            }
        }

        // convert A regs (loaded last iteration) to bf16 frags
        s16x8 a[2];
        if (isf) {
#pragma unroll
            for (int s2 = 0; s2 < 2; ++s2) {
                union { u16 u[8]; s16x8 v; } pk;
                pk.u[0] = f2bf(af[s2][0].x); pk.u[1] = f2bf(af[s2][0].y);
                pk.u[2] = f2bf(af[s2][0].z); pk.u[3] = f2bf(af[s2][0].w);
                pk.u[4] = f2bf(af[s2][1].x); pk.u[5] = f2bf(af[s2][1].y);
                pk.u[6] = f2bf(af[s2][1].z); pk.u[7] = f2bf(af[s2][1].w);
                a[s2] = pk.v;
            }
        } else {
            a[0] = *(const s16x8*)&ab[0];
            a[1] = *(const s16x8*)&ab[1];
        }

        if (kt + 1 < 32) {   // A prefetch next kt (in flight during MFMAs)
            const int k0 = (kt + 1) * 32;
            if (isf) {
                af[0][0] = *(const float4*)(xf0 + k0 + q * 8);
                af[0][1] = *(const float4*)(xf0 + k0 + q * 8 + 4);
                af[1][0] = *(const float4*)(xf1 + k0 + q * 8);
                af[1][1] = *(const float4*)(xf1 + k0 + q * 8 + 4);
            } else {
                ab[0] = *(const uint4*)(xb0 + k0 + q * 8);
                ab[1] = *(const uint4*)(xb1 + k0 + q * 8);
            }
        }

#pragma unroll
        for (int i = 0; i < 6; ++i) {
            int c = w * 6 + i;   // mat = c>>3, nt = c&7
            s16x8 b = *(const s16x8*)&Ws[buf][(c >> 3) * 4096 + ((c & 7) * 16 + r) * 32 + q * 8];
            acc[0][i] = __builtin_amdgcn_mfma_f32_16x16x32_bf16(a[0], b, acc[0][i], 0, 0, 0);
            acc[1][i] = __builtin_amdgcn_mfma_f32_16x16x32_bf16(a[1], b, acc[1][i], 0, 0, 0);
        }
    }

    // ---- epilogue: Q and K row-major via LDS bounce ----
    u16* outs[2] = {Qo, Ko};
    for (int m = 0; m < 2; ++m) {
        const float sc = (m == 0) ? 0.08838834764831845f : 1.0f;
        __syncthreads();
#pragma unroll
        for (int i = 0; i < 6; ++i) {
            int c = w * 6 + i;
            if ((c >> 3) == m) {
                int nt = c & 7;
#pragma unroll
                for (int s2 = 0; s2 < 2; ++s2)
#pragma unroll
                    for (int reg = 0; reg < 4; ++reg)
                        OsU.qk[(s2 * 16 + q * 4 + reg) * 136 + nt * 16 + r] = f2bf(acc[s2][i][reg] * sc);
            }
        }
        __syncthreads();
        u16* Out = outs[m];
#pragma unroll
        for (int it = 0; it < 2; ++it) {
            int c = tid + it * 256;
            int row = c >> 4, col = (c & 15) * 8;
            *(uint4*)(Out + (m0 + row) * H_ + col) = *(const uint4*)&OsU.qk[row * 136 + col];
        }
    }

    // ---- V transposed: OsU.vt[h][s_local], then Vt[b][h][s] global ----
    __syncthreads();
#pragma unroll
    for (int i = 0; i < 6; ++i) {
        int c = w * 6 + i;
        if ((c >> 3) == 2) {
            int nt = c & 7;
#pragma unroll
            for (int s2 = 0; s2 < 2; ++s2)
#pragma unroll
                for (int reg = 0; reg < 4; ++reg)
                    OsU.vt[(nt * 16 + r) * 40 + s2 * 16 + q * 4 + reg] = f2bf(acc[s2][i][reg]);
        }
    }
    __syncthreads();
    {
        const int bb = blockIdx.x >> 7;           // 128 blocks per batch
        const int s0 = (blockIdx.x & 127) * 32;
        // 128 h-rows x 32 s = 512 uint4 chunks: h = c>>2, sh = (c&3)*8
#pragma unroll
        for (int it = 0; it < 2; ++it) {
            int c = tid + it * 256;
            int h = c >> 2, sh = (c & 3) * 8;
            *(uint4*)(Vto + ((size_t)bb * H_ + h) * S_ + s0 + sh) =
                *(const uint4*)&OsU.vt[h * 40 + sh];
        }
    }
}

// ---------------------------------------------------------------------------
// Kernel 2: causal flash attention, QT=64, KT=128, 8 waves (512 threads).
// Round-4 post-mortem: all schedules pay ~5,500 cy/tile (latency-bound,
// no cache level saturated: 7.1 TB/s total = 11.5 B/cy/CU). The only
// untouched knob is TILES PER CU. QT=64 halves tile count while keeping
// the per-wave instruction mix and register footprint IDENTICAL to the
// proven r0 wave (32q x 32keys QK, 32q x 32h PV, ~100 VGPR). Balance
// without tail: causal pair (qtA=p, qtB=63-p) always has 33 tiles; split
// into chunks of 17/16 -> 256 identical blocks, exactly 1/CU. qtA output
// written directly; qtB (key-split across the 2 chunks) written as
// unnormalized f32 partials + l (linear: no max-pass) -> tiny combine.
// ---------------------------------------------------------------------------
__global__ __launch_bounds__(512) void attn_pair_kernel(
    const u16* __restrict__ Q, const u16* __restrict__ K, const u16* __restrict__ Vt,
    void* __restrict__ out, float* __restrict__ OP, float* __restrict__ LP,
    const int* __restrict__ dflag)
{
    __shared__ union {
        u16 ps[2][64 * 136];        // P double buffer (64 q-rows x 128 keys + pad)
        float of[64 * 132];         // epilogue bounce
    } U;
    __shared__ float lsumS[8][32];

    const int isf = *dflag;
    const int tid = threadIdx.x;
    const int w = tid >> 6, lane = tid & 63;
    const int qh = w >> 2;              // q-half (0: rows 0-31, 1: rows 32-63)
    const int kw = w & 3;               // key-quarter for QK / h-quarter for PV
    const int r = lane & 15, q = lane >> 4;
    const int bid = blockIdx.x;
    const int b = bid & 3;
    const int p = (bid >> 2) & 31;      // pair index
    const int c = bid >> 7;             // chunk 0/1
    const int qtA = p, qtB = 63 - p;
    const int nA = (p >> 1) + 1;        // tiles of qtA (1..16)
    const int nB = ((63 - p) >> 1) + 1; // tiles of qtB (17..32)
    const int m = 17 - nA;              // qtB tiles in chunk0 (1..16)

    const u16* Kg  = K  + (size_t)b * S_ * H_;
    const u16* Vtg = Vt + (size_t)b * H_ * S_;

    for (int seg = 0; seg < 2; ++seg) {
        int qt, jlo, jhi;
        bool direct;
        if (seg == 0) {
            if (c != 0) continue;
            qt = qtA; jlo = 0; jhi = nA; direct = true;
        } else {
            qt = qtB; jlo = (c == 0) ? 0 : m; jhi = (c == 0) ? m : nB; direct = false;
        }
        const int nQT = (qt >> 1) + 1;   // true tile count (diagonal at nQT-1)
        const u16* Qg = Q + ((size_t)b * S_ + (size_t)qt * 64) * H_;

        s16x8 qf[2][4];
#pragma unroll
        for (int M = 0; M < 2; ++M)
#pragma unroll
            for (int ks = 0; ks < 4; ++ks)
                qf[M][ks] = *(const s16x8*)(Qg + (size_t)(qh * 32 + M * 16 + r) * H_ + ks * 32 + q * 8);

        float lp[2][4];
#pragma unroll
        for (int M = 0; M < 2; ++M)
#pragma unroll
            for (int reg = 0; reg < 4; ++reg) lp[M][reg] = 0.f;

        f32x4 accO[2][2];
#pragma unroll
        for (int M = 0; M < 2; ++M)
#pragma unroll
            for (int ht = 0; ht < 2; ++ht) accO[M][ht] = (f32x4){0.f, 0.f, 0.f, 0.f};

        s16x8 kf[2][4];
#pragma unroll
        for (int t2 = 0; t2 < 2; ++t2)
#pragma unroll
            for (int ks = 0; ks < 4; ++ks)
                kf[t2][ks] = *(const s16x8*)(Kg + ((size_t)jlo * 128 + kw * 32 + t2 * 16 + r) * H_ + ks * 32 + q * 8);

        for (int j = jlo; j < jhi; ++j) {
            // ---- S = Q K^T on this wave's 32 q-rows x 32 keys ----
            f32x4 accS[2][2];
#pragma unroll
            for (int M = 0; M < 2; ++M)
#pragma unroll
                for (int t2 = 0; t2 < 2; ++t2) accS[M][t2] = (f32x4){0.f, 0.f, 0.f, 0.f};
#pragma unroll
            for (int ks = 0; ks < 4; ++ks)
#pragma unroll
                for (int t2 = 0; t2 < 2; ++t2)
#pragma unroll
                    for (int M = 0; M < 2; ++M)
                        accS[M][t2] = __builtin_amdgcn_mfma_f32_16x16x32_bf16(qf[M][ks], kf[t2][ks], accS[M][t2], 0, 0, 0);

            // ---- V frags: this wave's 32 h-cols (latency overlaps softmax+barrier) ----
            s16x8 vf[2][4];
#pragma unroll
            for (int ht = 0; ht < 2; ++ht)
#pragma unroll
                for (int ks = 0; ks < 4; ++ks)
                    vf[ht][ks] = *(const s16x8*)(Vtg + (size_t)(kw * 32 + ht * 16 + r) * S_ + (size_t)j * 128 + ks * 32 + q * 8);

            // ---- p = exp(s) (no max-pass), mask only the true diagonal tile ----
            const bool last = (j == nQT - 1);
            const int key0 = j * 128 + kw * 32 + r;
            u16* psb = &U.ps[j & 1][0];
#pragma unroll
            for (int M = 0; M < 2; ++M)
#pragma unroll
                for (int t2 = 0; t2 < 2; ++t2)
#pragma unroll
                    for (int reg = 0; reg < 4; ++reg) {
                        int key = key0 + t2 * 16;
                        int grow = qt * 64 + qh * 32 + M * 16 + q * 4 + reg;
                        float s = fminf(accS[M][t2][reg], 80.f);
                        float pv = __expf(s);
                        if (last && key > grow) pv = 0.f;
                        lp[M][reg] += pv;
                        psb[(qh * 32 + M * 16 + q * 4 + reg) * 136 + kw * 32 + t2 * 16 + r] = f2bf(pv);
                    }
            __syncthreads();   // P visible; prev PV done with other P buffer

            // ---- prefetch K frags for next tile (covered by PV MFMAs) ----
            if (j + 1 < jhi) {
#pragma unroll
                for (int t2 = 0; t2 < 2; ++t2)
#pragma unroll
                    for (int ks = 0; ks < 4; ++ks)
                        kf[t2][ks] = *(const s16x8*)(Kg + ((size_t)(j + 1) * 128 + kw * 32 + t2 * 16 + r) * H_ + ks * 32 + q * 8);
            }

            // ---- O += P V on this wave's 32 q-rows x 32 h-cols ----
#pragma unroll
            for (int ks = 0; ks < 4; ++ks) {
                s16x8 pa0 = *(const s16x8*)&psb[(size_t)(qh * 32 + r) * 136 + ks * 32 + q * 8];
                s16x8 pa1 = *(const s16x8*)&psb[(size_t)(qh * 32 + 16 + r) * 136 + ks * 32 + q * 8];
#pragma unroll
                for (int ht = 0; ht < 2; ++ht) {
                    accO[0][ht] = __builtin_amdgcn_mfma_f32_16x16x32_bf16(pa0, vf[ht][ks], accO[0][ht], 0, 0, 0);
                    accO[1][ht] = __builtin_amdgcn_mfma_f32_16x16x32_bf16(pa1, vf[ht][ks], accO[1][ht], 0, 0, 0);
                }
            }
        }

        // ---- l: reduce over r (keys in wave), then across the 4 kw waves ----
#pragma unroll
        for (int M = 0; M < 2; ++M)
#pragma unroll
            for (int reg = 0; reg < 4; ++reg) {
                float v = lp[M][reg];
                v += __shfl_xor(v, 1);
                v += __shfl_xor(v, 2);
                v += __shfl_xor(v, 4);
                v += __shfl_xor(v, 8);
                lp[M][reg] = v;
            }
        if (r == 0) {
#pragma unroll
            for (int M = 0; M < 2; ++M)
#pragma unroll
                for (int reg = 0; reg < 4; ++reg)
                    lsumS[w][M * 16 + q * 4 + reg] = lp[M][reg];
        }
        __syncthreads();   // lsumS ready; all PV done -> ps/U reusable

        if (direct) {
            float linv[2][4];
#pragma unroll
            for (int M = 0; M < 2; ++M)
#pragma unroll
                for (int reg = 0; reg < 4; ++reg) {
                    int row = M * 16 + q * 4 + reg;
                    linv[M][reg] = 1.0f / (lsumS[qh * 4 + 0][row] + lsumS[qh * 4 + 1][row] +
                                           lsumS[qh * 4 + 2][row] + lsumS[qh * 4 + 3][row]);
                }
#pragma unroll
            for (int M = 0; M < 2; ++M)
#pragma unroll
                for (int ht = 0; ht < 2; ++ht)
#pragma unroll
                    for (int reg = 0; reg < 4; ++reg)
                        U.of[(qh * 32 + M * 16 + q * 4 + reg) * 132 + kw * 32 + ht * 16 + r] =
                            accO[M][ht][reg] * linv[M][reg];
            __syncthreads();
            {
                const size_t obase = (size_t)b * S_ + (size_t)qt * 64;
                int row = tid >> 3, col = (tid & 7) * 16;
                const float* src = &U.of[row * 132 + col];
                if (isf) {
                    float* dst = (float*)out + (obase + row) * H_ + col;
#pragma unroll
                    for (int i = 0; i < 4; ++i)
                        *(float4*)(dst + i * 4) = *(const float4*)(src + i * 4);
                } else {
                    u16* dst = (u16*)out + (obase + row) * H_ + col;
#pragma unroll
                    for (int hh = 0; hh < 2; ++hh) {
                        union { u16 u[8]; uint4 v; } pk;
#pragma unroll
                        for (int i = 0; i < 8; ++i) pk.u[i] = f2bf(src[hh * 8 + i]);
                        *(uint4*)(dst + hh * 8) = pk.v;
                    }
                }
            }
            __syncthreads();   // U safe for next segment
        } else {
            const size_t slot = (size_t)((b * 32 + p) * 2 + c);
            if ((w == 0 || w == 4) && lane < 32)
                LP[slot * 64 + qh * 32 + lane] =
                    lsumS[qh * 4 + 0][lane] + lsumS[qh * 4 + 1][lane] +
                    lsumS[qh * 4 + 2][lane] + lsumS[qh * 4 + 3][lane];
            float* Os = OP + slot * 64 * 128;
#pragma unroll
            for (int M = 0; M < 2; ++M)
#pragma unroll
                for (int ht = 0; ht < 2; ++ht)
#pragma unroll
                    for (int reg = 0; reg < 4; ++reg)
                        Os[(qh * 32 + M * 16 + q * 4 + reg) * 128 + kw * 32 + ht * 16 + r] =
                            accO[M][ht][reg];
            __syncthreads();   // lsumS/ps safe for next segment
        }
    }
}

// ---------------------------------------------------------------------------
// Kernel 3: combine the key-split long q-tiles (qt64 = 32..63 per batch):
// O = (O0 + O1) / (l0 + l1). Grid 128 = 4b x 32qt, 256 threads.
// ---------------------------------------------------------------------------
__global__ __launch_bounds__(256) void combine_kernel(
    const float* __restrict__ OP, const float* __restrict__ LP,
    void* __restrict__ out, const int* __restrict__ dflag)
{
    const int isf = *dflag;
    const int bid = blockIdx.x;
    const int b = bid >> 5;
    const int qtl = bid & 31;            // qt64 = 32 + qtl, pair p = 63 - qt64 = 31 - qtl
    const int p = 31 - qtl;
    const size_t s0 = (size_t)((b * 32 + p) * 2);
    const int tid = threadIdx.x;
    const int row = tid >> 2;            // 0..63
    const int col0 = (tid & 3) * 32;     // 0,32,64,96

    const float* O0 = OP + (s0 * 64 + row) * 128 + col0;
    const float* O1 = OP + ((s0 + 1) * 64 + row) * 128 + col0;
    const float l = LP[s0 * 64 + row] + LP[(s0 + 1) * 64 + row];
    const float inv = 1.0f / l;

    float vals[32];
#pragma unroll
    for (int i = 0; i < 8; ++i) {
        float4 a = *(const float4*)(O0 + i * 4);
        float4 bb = *(const float4*)(O1 + i * 4);
        vals[i * 4 + 0] = (a.x + bb.x) * inv;
        vals[i * 4 + 1] = (a.y + bb.y) * inv;
        vals[i * 4 + 2] = (a.z + bb.z) * inv;
        vals[i * 4 + 3] = (a.w + bb.w) * inv;
    }

    const size_t orow = (size_t)b * S_ + (size_t)(32 + qtl) * 64 + row;
    if (isf) {
        float* dst = (float*)out + orow * H_ + col0;
#pragma unroll
        for (int i = 0; i < 8; ++i)
            *(float4*)(dst + i * 4) = *(const float4*)(&vals[i * 4]);
    } else {
        u16* dst = (u16*)out + orow * H_ + col0;
#pragma unroll
        for (int hh = 0; hh < 4; ++hh) {
            union { u16 u[8]; uint4 v; } pk;
#pragma unroll
            for (int i = 0; i < 8; ++i) pk.u[i] = f2bf(vals[hh * 8 + i]);
            *(uint4*)(dst + hh * 8) = pk.v;
        }
    }
}

extern "C" void kernel_launch(void* const* d_in, const int* in_sizes, int n_in,
                              void* d_out, int out_size, void* d_ws, size_t ws_size,
                              hipStream_t stream) {
    (void)in_sizes; (void)n_in; (void)out_size; (void)ws_size;
    const void* X  = d_in[0];
    const void* Wq = d_in[1];
    const void* Wk = d_in[2];
    const void* Wv = d_in[3];

    int* dflag = (int*)d_ws;                          // 256 B header
    u16* Qw = (u16*)((char*)d_ws + 256);
    const size_t n = (size_t)B_ * S_ * H_;            // 2M elems per tensor
    u16* Kw = Qw + n;
    u16* Vtw = Kw + n;                                // V stored transposed [b][h][s]
    u16* Wt = Vtw + n;                                // 3*1024*128 bf16 = 768 KB
    float* OP = (float*)(Wt + 3 * 1024 * 128);        // 256 slots x 64x128 f32 = 8 MB
    float* LP = OP + (size_t)256 * 64 * 128;          // 256 x 64 f32 = 64 KB

    detect_dtype_kernel<<<1, 256, 0, stream>>>((const u32*)Wq, dflag);
    prep_w_kernel<<<dim3(32, 3), 256, 0, stream>>>(Wq, Wk, Wv, Wt, dflag);
    qkv_kernel<<<512, 256, 0, stream>>>(X, Wt, Qw, Kw, Vtw, dflag);
    attn_pair_kernel<<<256, 512, 0, stream>>>(Qw, Kw, Vtw, d_out, OP, LP, dflag);
    combine_kernel<<<128, 256, 0, stream>>>(OP, LP, d_out, dflag);
}

// Round 6
// 207.092 us; speedup vs baseline: 1.0608x; 1.0608x over previous
//
#include <hip/hip_runtime.h>
#include <hip/hip_bf16.h>

#define B_ 4
#define S_ 4096
#define D_ 1024
#define H_ 128

typedef unsigned short u16;
typedef unsigned int u32;
typedef short s16x8 __attribute__((ext_vector_type(8)));   // 8 bf16 (4 VGPRs)
typedef float f32x4 __attribute__((ext_vector_type(4)));   // MFMA 16x16 acc
typedef float f32x16 __attribute__((ext_vector_type(16))); // MFMA 32x32 acc

__device__ __forceinline__ u16 f2bf(float f) {
    u32 x = __float_as_uint(f);
    u32 r = x + 0x7fffu + ((x >> 16) & 1u);   // RNE
    return (u16)(r >> 16);
}

// v_cvt_pk_bf16_f32: dst = {bf16(a) lo16, bf16(b) hi16}
__device__ __forceinline__ u32 cvtpk_bf16(float a, float b) {
    u32 r;
    asm("v_cvt_pk_bf16_f32 %0, %1, %2" : "=v"(r) : "v"(a), "v"(b));
    return r;
}
// v_permlane32_swap_b32: exchanges x.hi-lanes <-> y.lo-lanes (both updated)
__device__ __forceinline__ void pl32swap(u32& x, u32& y) {
    asm("v_permlane32_swap_b32 %0, %1" : "+v"(x), "+v"(y));
}

// async global->LDS, 16 B per lane (m97 pattern; zero staging VGPRs)
__device__ __forceinline__ void gl_lds16(const u16* g, u16* l) {
    __builtin_amdgcn_global_load_lds(
        (const __attribute__((address_space(1))) u32*)g,
        (__attribute__((address_space(3))) u32*)l, 16, 0, 0);
}

// ---------------------------------------------------------------------------
// Kernel 0: input dtype detection (fp32 vs bf16). Verified in round 3.
// ---------------------------------------------------------------------------
__global__ void detect_dtype_kernel(const u32* __restrict__ w, int* __restrict__ flag) {
    __shared__ int smax[256];
    const int tid = threadIdx.x;
    int m = 0;
    for (int i = tid; i < 1024; i += 256) {
        u32 x = w[i];
        m = max(m, max((int)((x >> 7) & 0xFF), (int)((x >> 23) & 0xFF)));
    }
    smax[tid] = m;
    __syncthreads();
    if (tid == 0) {
        int mm = 0;
        for (int i = 0; i < 256; ++i) mm = max(mm, smax[i]);
        *flag = (mm >= 200) ? 1 : 0;
    }
}

// ---------------------------------------------------------------------------
// Kernel 0b: W -> Wt, bf16, transposed + tiled so a B-fragment is 16 B
// contiguous: Wt[((mat*32+kt)*128 + n)*32 + k]. Tile (mat,kt) = 8 KB.
// ---------------------------------------------------------------------------
__global__ __launch_bounds__(256) void prep_w_kernel(
    const void* __restrict__ Wq, const void* __restrict__ Wk, const void* __restrict__ Wv,
    u16* __restrict__ Wt, const int* __restrict__ dflag)
{
    const int kt = blockIdx.x, mat = blockIdx.y;
    const void* W = (mat == 0) ? Wq : (mat == 1) ? Wk : Wv;
    const int isf = *dflag;
    const int t = threadIdx.x;
    const int kk = t >> 3;            // 0..31 (k within tile)
    const int n0 = (t & 7) * 16;      // 16 n per thread
    u16 vals[16];
    if (isf) {
        const float* wp = (const float*)W + (size_t)(kt * 32 + kk) * H_ + n0;
#pragma unroll
        for (int i = 0; i < 16; ++i) vals[i] = f2bf(wp[i]);
    } else {
        const u16* wp = (const u16*)W + (size_t)(kt * 32 + kk) * H_ + n0;
#pragma unroll
        for (int i = 0; i < 16; ++i) vals[i] = wp[i];
    }
    const size_t base = (size_t)(mat * 32 + kt) * 128;
#pragma unroll
    for (int i = 0; i < 16; ++i)
        Wt[(base + n0 + i) * 32 + kk] = vals[i];
}

// ---------------------------------------------------------------------------
// Kernel 1: fused QKV GEMM v4 (unchanged from measured-good round).
// ---------------------------------------------------------------------------
__global__ __launch_bounds__(256) void qkv_kernel(
    const void* __restrict__ Xv, const u16* __restrict__ Wt,
    u16* __restrict__ Qo, u16* __restrict__ Ko, u16* __restrict__ Vto,
    const int* __restrict__ dflag)
{
    __shared__ u16 Ws[2][384 * 32];                              // 2 x 24 KB
    __shared__ union { u16 qk[32 * 136]; u16 vt[128 * 40]; } OsU; // 10.2 KB

    const int isf = *dflag;
    const int tid = threadIdx.x;
    const int w = tid >> 6, lane = tid & 63;
    const int r = lane & 15, q = lane >> 4;
    const size_t m0 = (size_t)blockIdx.x * 32;

    f32x4 acc[2][6];   // [row strip][frag]
#pragma unroll
    for (int s2 = 0; s2 < 2; ++s2)
#pragma unroll
        for (int i = 0; i < 6; ++i) acc[s2][i] = (f32x4){0.f, 0.f, 0.f, 0.f};

    const float* xf0 = (const float*)Xv + (m0 + r) * D_;
    const float* xf1 = (const float*)Xv + (m0 + 16 + r) * D_;
    const u16*   xb0 = (const u16*)Xv + (m0 + r) * D_;
    const u16*   xb1 = (const u16*)Xv + (m0 + 16 + r) * D_;

    float4 af[2][2];   // fp32 A prefetch (2 strips x 8 floats)
    uint4  ab[2];      // bf16 A prefetch

    // ---- async-stage W tile kt=0 into Ws[0] ----
#pragma unroll
    for (int i = 0; i < 6; ++i) {
        int c = tid + i * 256;      // 1536 chunks of 16 B; mat = c>>9
        gl_lds16(Wt + (size_t)((c >> 9) * 32) * 4096 + (c & 511) * 8, &Ws[0][c * 8]);
    }
    // ---- A prefetch kt=0 ----
    if (isf) {
        af[0][0] = *(const float4*)(xf0 + q * 8);
        af[0][1] = *(const float4*)(xf0 + q * 8 + 4);
        af[1][0] = *(const float4*)(xf1 + q * 8);
        af[1][1] = *(const float4*)(xf1 + q * 8 + 4);
    } else {
        ab[0] = *(const uint4*)(xb0 + q * 8);
        ab[1] = *(const uint4*)(xb1 + q * 8);
    }

    for (int kt = 0; kt < 32; ++kt) {
        const int buf = kt & 1;
        __syncthreads();   // drains vmcnt: Ws[buf] + A(kt) ready; readers of Ws[buf^1] done

        if (kt + 1 < 32) {  // async-stage W tile kt+1 into the other buffer
#pragma unroll
            for (int i = 0; i < 6; ++i) {
                int c = tid + i * 256;
                gl_lds16(Wt + (size_t)((c >> 9) * 32 + kt + 1) * 4096 + (c & 511) * 8,
                         &Ws[buf ^ 1][c * 8]);
            }
        }

        // convert A regs (loaded last iteration) to bf16 frags
        s16x8 a[2];
        if (isf) {
#pragma unroll
            for (int s2 = 0; s2 < 2; ++s2) {
                union { u16 u[8]; s16x8 v; } pk;
                pk.u[0] = f2bf(af[s2][0].x); pk.u[1] = f2bf(af[s2][0].y);
                pk.u[2] = f2bf(af[s2][0].z); pk.u[3] = f2bf(af[s2][0].w);
                pk.u[4] = f2bf(af[s2][1].x); pk.u[5] = f2bf(af[s2][1].y);
                pk.u[6] = f2bf(af[s2][1].z); pk.u[7] = f2bf(af[s2][1].w);
                a[s2] = pk.v;
            }
        } else {
            a[0] = *(const s16x8*)&ab[0];
            a[1] = *(const s16x8*)&ab[1];
        }

        if (kt + 1 < 32) {   // A prefetch next kt (in flight during MFMAs)
            const int k0 = (kt + 1) * 32;
            if (isf) {
                af[0][0] = *(const float4*)(xf0 + k0 + q * 8);
                af[0][1] = *(const float4*)(xf0 + k0 + q * 8 + 4);
                af[1][0] = *(const float4*)(xf1 + k0 + q * 8);
                af[1][1] = *(const float4*)(xf1 + k0 + q * 8 + 4);
            } else {
                ab[0] = *(const uint4*)(xb0 + k0 + q * 8);
                ab[1] = *(const uint4*)(xb1 + k0 + q * 8);
            }
        }

#pragma unroll
        for (int i = 0; i < 6; ++i) {
            int c = w * 6 + i;   // mat = c>>3, nt = c&7
            s16x8 b = *(const s16x8*)&Ws[buf][(c >> 3) * 4096 + ((c & 7) * 16 + r) * 32 + q * 8];
            acc[0][i] = __builtin_amdgcn_mfma_f32_16x16x32_bf16(a[0], b, acc[0][i], 0, 0, 0);
            acc[1][i] = __builtin_amdgcn_mfma_f32_16x16x32_bf16(a[1], b, acc[1][i], 0, 0, 0);
        }
    }

    // ---- epilogue: Q and K row-major via LDS bounce ----
    u16* outs[2] = {Qo, Ko};
    for (int m = 0; m < 2; ++m) {
        const float sc = (m == 0) ? 0.08838834764831845f : 1.0f;
        __syncthreads();
#pragma unroll
        for (int i = 0; i < 6; ++i) {
            int c = w * 6 + i;
            if ((c >> 3) == m) {
                int nt = c & 7;
#pragma unroll
                for (int s2 = 0; s2 < 2; ++s2)
#pragma unroll
                    for (int reg = 0; reg < 4; ++reg)
                        OsU.qk[(s2 * 16 + q * 4 + reg) * 136 + nt * 16 + r] = f2bf(acc[s2][i][reg] * sc);
            }
        }
        __syncthreads();
        u16* Out = outs[m];
#pragma unroll
        for (int it = 0; it < 2; ++it) {
            int c = tid + it * 256;
            int row = c >> 4, col = (c & 15) * 8;
            *(uint4*)(Out + (m0 + row) * H_ + col) = *(const uint4*)&OsU.qk[row * 136 + col];
        }
    }

    // ---- V transposed: OsU.vt[h][s_local], then Vt[b][h][s] global ----
    __syncthreads();
#pragma unroll
    for (int i = 0; i < 6; ++i) {
        int c = w * 6 + i;
        if ((c >> 3) == 2) {
            int nt = c & 7;
#pragma unroll
            for (int s2 = 0; s2 < 2; ++s2)
#pragma unroll
                for (int reg = 0; reg < 4; ++reg)
                    OsU.vt[(nt * 16 + r) * 40 + s2 * 16 + q * 4 + reg] = f2bf(acc[s2][i][reg]);
        }
    }
    __syncthreads();
    {
        const int bb = blockIdx.x >> 7;           // 128 blocks per batch
        const int s0 = (blockIdx.x & 127) * 32;
        // 128 h-rows x 32 s = 512 uint4 chunks: h = c>>2, sh = (c&3)*8
#pragma unroll
        for (int it = 0; it < 2; ++it) {
            int c = tid + it * 256;
            int h = c >> 2, sh = (c & 3) * 8;
            *(uint4*)(Vto + ((size_t)bb * H_ + h) * S_ + s0 + sh) =
                *(const uint4*)&OsU.vt[h * 40 + sh];
        }
    }
}

// ---------------------------------------------------------------------------
// Kernel 2: causal flash attention — SWAPPED-QK^T IN-REGISTER SOFTMAX.
// Round-5 post-mortem: time is invariant to occupancy/blocks/traffic and
// proportional ONLY to per-wave serial work => the per-tile chain
// (QK -> exp/f2bf/LDS-write -> barrier(vmcnt drain) -> LDS-read -> PV) is
// the wall; phase-locked waves can't hide each other's stalls. This version
// DELETES the chain: mfma_32x32x16(K,Q) puts S^T with qrow=lane&31 and 16
// key-scores in regs; softmax is lane-local; P->A-frag assembly is
// 8 cvt_pk + 4 permlane32_swap (m214/T12 recipe, lane algebra verified);
// Q/K/V frags load DIRECTLY from global (16B/lane, layouts match natively).
// NO barrier, NO LDS in the k-loop. Each wave owns one 32-row q-tile; a
// block's 4 waves split keys round-robin (linear partials, no max-pass)
// and merge once via LDS at block end (one barrier total). Pairing grid.
// ---------------------------------------------------------------------------
__global__ __launch_bounds__(256) void attn_kernel(
    const u16* __restrict__ Q, const u16* __restrict__ K, const u16* __restrict__ Vt,
    void* __restrict__ out, const int* __restrict__ dflag)
{
    __shared__ float opS[4][32][128];   // per-wave unnormalized O partials (64 KB)
    __shared__ float lpS[4][32];        // per-wave l partials

    const int isf = *dflag;
    const int tid = threadIdx.x;
    const int w = tid >> 6, lane = tid & 63;
    const int l31 = lane & 31, hi = lane >> 5;
    const int bid = blockIdx.x;
    const int b = bid & 3;
    const int qt = (bid < 256) ? (bid >> 2) : (127 - ((bid - 256) >> 2));

    const u16* Qg  = Q  + ((size_t)b * S_ + (size_t)qt * 32) * H_;
    const u16* Kg  = K  + (size_t)b * S_ * H_;
    const u16* Vtg = Vt + (size_t)b * H_ * S_;

    // Q as B-operand frags: lane -> qrow = l31, k(h) = sl*16 + hi*8 + [0..8)
    s16x8 qf[8];
#pragma unroll
    for (int sl = 0; sl < 8; ++sl)
        qf[sl] = *(const s16x8*)(Qg + (size_t)l31 * H_ + sl * 16 + hi * 8);

    f32x16 accO[4];
#pragma unroll
    for (int hg = 0; hg < 4; ++hg)
#pragma unroll
        for (int i = 0; i < 16; ++i) accO[hg][i] = 0.f;
    float lp = 0.f;

    // K as A-operand frags for first chunk: lane -> key = l31, k(h) likewise
    s16x8 kf[8];
    if (w <= qt) {
#pragma unroll
        for (int sl = 0; sl < 8; ++sl)
            kf[sl] = *(const s16x8*)(Kg + ((size_t)w * 32 + l31) * H_ + sl * 16 + hi * 8);
    }

    for (int c = w; c <= qt; c += 4) {
        const int kb = c * 32;

        // V as B-operand frags: lane -> h = hg*32+l31, k(key) = ks*16 + hi*8 + [0..8)
        s16x8 vf[4][2];
#pragma unroll
        for (int hg = 0; hg < 4; ++hg)
#pragma unroll
            for (int ks = 0; ks < 2; ++ks)
                vf[hg][ks] = *(const s16x8*)(Vtg + (size_t)(hg * 32 + l31) * S_ + kb + ks * 16 + hi * 8);

        // ---- S^T = K Q^T : lane holds qrow = l31, key(r,hi) = (r&3)+8*(r>>2)+4*hi ----
        f32x16 sacc;
#pragma unroll
        for (int i = 0; i < 16; ++i) sacc[i] = 0.f;
#pragma unroll
        for (int sl = 0; sl < 8; ++sl)
            sacc = __builtin_amdgcn_mfma_f32_32x32x16_bf16(kf[sl], qf[sl], sacc, 0, 0, 0);

        // ---- prefetch K frags for this wave's next chunk (covered by softmax+PV) ----
        if (c + 4 <= qt) {
#pragma unroll
            for (int sl = 0; sl < 8; ++sl)
                kf[sl] = *(const s16x8*)(Kg + ((size_t)(kb + 128) + l31) * H_ + sl * 16 + hi * 8);
        }

        // ---- lane-local softmax (no max-pass; clamp 80), mask own diagonal chunk ----
        const bool diag = (c == qt);
        float p[16];
#pragma unroll
        for (int r = 0; r < 16; ++r) {
            float s = fminf(sacc[r], 80.f);
            float pv = __expf(s);
            if (diag && ((r & 3) + 8 * (r >> 2) + 4 * hi) > l31) pv = 0.f;
            lp += pv;
            p[r] = pv;
        }

        // ---- P -> PV A-frags: 8 cvt_pk + 4 permlane32_swap (T12 recipe) ----
        // slice0 (keys 0..15): slots from p0..p7; slice1 (keys 16..31): p8..p15
        u32 w01 = cvtpk_bf16(p[0], p[1]),  w23 = cvtpk_bf16(p[2], p[3]);
        u32 w45 = cvtpk_bf16(p[4], p[5]),  w67 = cvtpk_bf16(p[6], p[7]);
        pl32swap(w01, w45);   // -> slot0, slot2
        pl32swap(w23, w67);   // -> slot1, slot3
        u32 x01 = cvtpk_bf16(p[8], p[9]),  x23 = cvtpk_bf16(p[10], p[11]);
        u32 x45 = cvtpk_bf16(p[12], p[13]), x67 = cvtpk_bf16(p[14], p[15]);
        pl32swap(x01, x45);
        pl32swap(x23, x67);
        union { u32 u[4]; s16x8 v; } pa0, pa1;
        pa0.u[0] = w01; pa0.u[1] = w23; pa0.u[2] = w45; pa0.u[3] = w67;
        pa1.u[0] = x01; pa1.u[1] = x23; pa1.u[2] = x45; pa1.u[3] = x67;

        // ---- O += P V : D lane holds h = hg*32+l31, qrow(r,hi) ----
#pragma unroll
        for (int hg = 0; hg < 4; ++hg) {
            accO[hg] = __builtin_amdgcn_mfma_f32_32x32x16_bf16(pa0.v, vf[hg][0], accO[hg], 0, 0, 0);
            accO[hg] = __builtin_amdgcn_mfma_f32_32x32x16_bf16(pa1.v, vf[hg][1], accO[hg], 0, 0, 0);
        }
    }

    // ---- combine the two key-halves of l (lane pair L, L+32) ----
    lp += __shfl_xor(lp, 32);

    // ---- flush per-wave partials to LDS ----
#pragma unroll
    for (int hg = 0; hg < 4; ++hg)
#pragma unroll
        for (int r = 0; r < 16; ++r)
            opS[w][(r & 3) + 8 * (r >> 2) + 4 * hi][hg * 32 + l31] = accO[hg][r];
    if (lane < 32) lpS[w][l31] = lp;
    __syncthreads();

    // ---- block combine: sum 4 wave partials, normalize, store ----
    {
        const int q = tid >> 3;              // 0..31
        const int hs = (tid & 7) * 16;       // 0..112
        const float l = lpS[0][q] + lpS[1][q] + lpS[2][q] + lpS[3][q];
        const float inv = 1.0f / l;
        float vals[16];
#pragma unroll
        for (int i = 0; i < 16; i += 4) {
            float4 a0 = *(const float4*)&opS[0][q][hs + i];
            float4 a1 = *(const float4*)&opS[1][q][hs + i];
            float4 a2 = *(const float4*)&opS[2][q][hs + i];
            float4 a3 = *(const float4*)&opS[3][q][hs + i];
            vals[i + 0] = (a0.x + a1.x + a2.x + a3.x) * inv;
            vals[i + 1] = (a0.y + a1.y + a2.y + a3.y) * inv;
            vals[i + 2] = (a0.z + a1.z + a2.z + a3.z) * inv;
            vals[i + 3] = (a0.w + a1.w + a2.w + a3.w) * inv;
        }
        const size_t orow = (size_t)b * S_ + (size_t)qt * 32 + q;
        if (isf) {
            float* dst = (float*)out + orow * H_ + hs;
#pragma unroll
            for (int i = 0; i < 4; ++i)
                *(float4*)(dst + i * 4) = *(const float4*)(&vals[i * 4]);
        } else {
            u16* dst = (u16*)out + orow * H_ + hs;
#pragma unroll
            for (int hh = 0; hh < 2; ++hh) {
                union { u16 u[8]; uint4 v; } pk;
#pragma unroll
                for (int i = 0; i < 8; ++i) pk.u[i] = f2bf(vals[hh * 8 + i]);
                *(uint4*)(dst + hh * 8) = pk.v;
            }
        }
    }
}

extern "C" void kernel_launch(void* const* d_in, const int* in_sizes, int n_in,
                              void* d_out, int out_size, void* d_ws, size_t ws_size,
                              hipStream_t stream) {
    (void)in_sizes; (void)n_in; (void)out_size; (void)ws_size;
    const void* X  = d_in[0];
    const void* Wq = d_in[1];
    const void* Wk = d_in[2];
    const void* Wv = d_in[3];

    int* dflag = (int*)d_ws;                          // 256 B header
    u16* Qw = (u16*)((char*)d_ws + 256);
    const size_t n = (size_t)B_ * S_ * H_;            // 2M elems per tensor
    u16* Kw = Qw + n;
    u16* Vtw = Kw + n;                                // V stored transposed [b][h][s]
    u16* Wt = Vtw + n;                                // 3*1024*128 bf16 = 768 KB

    detect_dtype_kernel<<<1, 256, 0, stream>>>((const u32*)Wq, dflag);
    prep_w_kernel<<<dim3(32, 3), 256, 0, stream>>>(Wq, Wk, Wv, Wt, dflag);
    qkv_kernel<<<512, 256, 0, stream>>>(X, Wt, Qw, Kw, Vtw, dflag);
    attn_kernel<<<512, 256, 0, stream>>>(Qw, Kw, Vtw, d_out, dflag);
}